// Round 1
// baseline (159.690 us; speedup 1.0000x reference)
//
#include <hip/hip_runtime.h>

// Medical2DSliceRenderer on MI355X (gfx950)
//
// Math: per pixel p, slice s, chunk c:
//   S1[c] = sum_g g*op,  S2[c] = sum_g g^2*op*ft   (g = exp(-0.5*maha)*mask)
//   img += (1-acc)*S2[c];  acc += (1-acc)*S1[c]    (chunks sequential)
// g = exp2( qa*dx^2 + qb*dx*dy + qd*dy^2 ) with -0.5*log2(e) folded into q*.
//
// Kernels:
//   1. max_scale_kernel: max_dist = 3*max(scales[:,2])        (1 block)
//   2. prep_kernel: per-(slice,gaussian) {mu2d, qa,qb,qd, op*mask, op*ft*mask}
//      -> ws (4 x 4096 x 2 float4 = 512KB)
//   3. render_kernel: 512 blocks x 512 thr; block = 128 px of one slice,
//      4-way gaussian split across waves; chunk staged in LDS (32KB);
//      per-chunk partials combined in LDS, sequential acc recursion at end.

#define EPSV 1e-6f
#define NG   4096
#define HH   128
#define WW   128
#define PP   (HH*WW)
#define NSL  4
#define SPLIT 4
#define PXB  128
#define GPS  256          // gaussians per split per chunk (1024/4)

__global__ void max_scale_kernel(const float* __restrict__ scales,
                                 float* __restrict__ wsf) {
    __shared__ float red[256];
    int tid = threadIdx.x;
    float m = -1e30f;
    for (int i = tid; i < NG; i += 256) m = fmaxf(m, scales[i*3+2]);
    red[tid] = m;
    __syncthreads();
    for (int s = 128; s > 0; s >>= 1) {
        if (tid < s) red[tid] = fmaxf(red[tid], red[tid+s]);
        __syncthreads();
    }
    if (tid == 0) wsf[0] = 3.0f * red[0];
}

__global__ void prep_kernel(const float* __restrict__ means,
                            const float* __restrict__ scales,
                            const float* __restrict__ rots,
                            const float* __restrict__ ops,
                            const float* __restrict__ fts,
                            const float* __restrict__ wsf,
                            float4* __restrict__ gdata) {
    int g = blockIdx.x * 256 + threadIdx.x;
    if (g >= NG) return;

    float qw = rots[g*4+0], qx = rots[g*4+1], qy = rots[g*4+2], qz = rots[g*4+3];
    float inorm = rsqrtf(qw*qw + qx*qx + qy*qy + qz*qz);
    qw *= inorm; qx *= inorm; qy *= inorm; qz *= inorm;

    float s0 = scales[g*3+0], s1 = scales[g*3+1], s2 = scales[g*3+2];

    float r00 = 1.f - 2.f*(qy*qy + qz*qz), r01 = 2.f*(qx*qy - qw*qz), r02 = 2.f*(qx*qz + qw*qy);
    float r10 = 2.f*(qx*qy + qw*qz), r11 = 1.f - 2.f*(qx*qx + qz*qz), r12 = 2.f*(qy*qz - qw*qx);
    float r20 = 2.f*(qx*qz - qw*qy), r21 = 2.f*(qy*qz + qw*qx), r22 = 1.f - 2.f*(qx*qx + qy*qy);

    float a00 = r00*s0, a01 = r01*s1, a02 = r02*s2;
    float a10 = r10*s0, a11 = r11*s1, a12 = r12*s2;
    float a20 = r20*s0, a21 = r21*s1, a22 = r22*s2;

    // cov = RS * RS^T (needed entries)
    float c00 = a00*a00 + a01*a01 + a02*a02;
    float c01 = a00*a10 + a01*a11 + a02*a12;
    float c02 = a00*a20 + a01*a21 + a02*a22;
    float c11 = a10*a10 + a11*a11 + a12*a12;
    float c12 = a10*a20 + a11*a21 + a12*a22;
    float c22 = a20*a20 + a21*a21 + a22*a22;

    float izz = 1.0f / (c22 + EPSV);
    float kx = c02 * izz, ky = c12 * izz;
    float sa = c00 - c02*c02*izz + EPSV;
    float sb = c01 - c02*c12*izz;
    float sd = c11 - c12*c12*izz + EPSV;
    float det = sa*sd - sb*sb;
    float idet = 1.0f / det;

    const float C0 = -0.72134752044448170f;   // -0.5 * log2(e)
    float qa = C0 * sd * idet;
    float qb = C0 * (-2.0f * sb * idet);
    float qd = C0 * sa * idet;

    float mx = means[g*3+0], my = means[g*3+1], mz = means[g*3+2];
    float op = ops[g], ft = fts[g];
    float maxd = wsf[0];

    #pragma unroll
    for (int s = 0; s < NSL; ++s) {
        float z = -0.15f + 0.1f * (float)s;
        float zoff = z - mz;
        float m2x = mx + kx * zoff;
        float m2y = my + ky * zoff;
        bool msk = fabsf(mz - z) < maxd;
        float o  = msk ? op      : 0.f;
        float of = msk ? op * ft : 0.f;
        gdata[(s*NG + g)*2 + 0] = make_float4(m2x, m2y, qa, qb);
        gdata[(s*NG + g)*2 + 1] = make_float4(qd, o, of, 0.f);
    }
}

__global__ __launch_bounds__(512, 4)
void render_kernel(const float4* __restrict__ gdata, float* __restrict__ out) {
    __shared__ float4 sg[2048];            // one chunk: 1024 gaussians x 2 float4 (32KB)
    __shared__ float parts[SPLIT][PXB][9]; // per-chunk partial sums, padded (18KB)

    int tid   = threadIdx.x;
    int px    = tid & (PXB-1);
    int split = tid >> 7;                  // 0..3
    int slice = blockIdx.x >> 7;           // 0..3
    int tile  = blockIdx.x & 127;
    int pxg   = tile * PXB + px;           // pixel in slice, 0..16383
    int row   = pxg >> 7, col = pxg & 127;
    float x = (float)col * (2.0f/127.0f) - 1.0f;
    float y = (float)row * (2.0f/127.0f) - 1.0f;

    const float4* gs = gdata + slice * (NG*2);

    #pragma unroll
    for (int c = 0; c < 4; ++c) {
        __syncthreads();   // protect sg reads of previous chunk
        // stage chunk c (coalesced, 4 float4 per thread)
        #pragma unroll
        for (int i = 0; i < 4; ++i)
            sg[tid + i*512] = gs[c*2048 + tid + i*512];
        __syncthreads();

        float a1 = 0.f, a2 = 0.f;
        const float4* p = &sg[split * (GPS*2)];
        #pragma unroll 8
        for (int g = 0; g < GPS; ++g) {
            float4 A = p[2*g+0];           // mu2dx, mu2dy, qa, qb
            float4 B = p[2*g+1];           // qd, op, op*ft, pad
            float dx = x - A.x;
            float dy = y - A.y;
            float t  = fmaf(A.z, dx, A.w * dy);       // qa*dx + qb*dy
            float m  = fmaf(dx, t, B.x * dy * dy);    // + qd*dy^2
            float gv = __builtin_amdgcn_exp2f(m);
            a1 = fmaf(gv, B.y, a1);
            a2 = fmaf(gv, gv * B.z, a2);
        }
        parts[split][px][c]     = a1;
        parts[split][px][c + 4] = a2;
    }
    __syncthreads();

    if (split == 0) {
        float img = 0.f, acc = 0.f;
        #pragma unroll
        for (int c = 0; c < 4; ++c) {
            float S1 = parts[0][px][c]   + parts[1][px][c]
                     + parts[2][px][c]   + parts[3][px][c];
            float S2 = parts[0][px][c+4] + parts[1][px][c+4]
                     + parts[2][px][c+4] + parts[3][px][c+4];
            float om = 1.0f - acc;
            img = fmaf(om, S2, img);
            acc = fmaf(om, S1, acc);
        }
        out[slice * PP + pxg] = img;
    }
}

extern "C" void kernel_launch(void* const* d_in, const int* in_sizes, int n_in,
                              void* d_out, int out_size, void* d_ws, size_t ws_size,
                              hipStream_t stream) {
    const float* means  = (const float*)d_in[0];
    const float* scales = (const float*)d_in[1];
    const float* rots   = (const float*)d_in[2];
    const float* ops    = (const float*)d_in[3];
    const float* fts    = (const float*)d_in[4];
    float* out = (float*)d_out;

    float*  wsf   = (float*)d_ws;
    float4* gdata = (float4*)((char*)d_ws + 256);   // 4*4096*2 float4 = 512KB

    max_scale_kernel<<<1, 256, 0, stream>>>(scales, wsf);
    prep_kernel<<<NG/256, 256, 0, stream>>>(means, scales, rots, ops, fts, wsf, gdata);
    render_kernel<<<NSL*(PP/PXB), 512, 0, stream>>>(gdata, out);
}

// Round 2
// 147.671 us; speedup vs baseline: 1.0814x; 1.0814x over previous
//
#include <hip/hip_runtime.h>

// Medical2DSliceRenderer on MI355X (gfx950) — round 2
//
// Math per pixel p, slice s, chunk c:
//   S1[c] = sum_g exp2(C0*maha + log2(op*mask))                  (= g*op)
//   S2[c] = sum_g (g*op)^2 * (ft/op)                             (= g^2*op*ft)
//   img += (1-acc)*S2[c];  acc += (1-acc)*S1[c]   (4-step scalar recursion)
//
// Round-2 structural change: gaussian params are WAVE-UNIFORM -> fetch them
// on the scalar pipe (s_load) instead of broadcast ds_read_b128 (which was
// saturating the per-CU LDS pipe at ~33K b128/CU). readfirstlane on `split`
// makes the address provably uniform so hipcc emits s_load_dwordx8.

#define EPSV 1e-6f
#define NG   4096
#define PP   16384
#define NSL  4
#define SPLIT 8
#define PXW  64          // pixels per block (one wave of pixels)
#define GPW  128         // gaussians per wave per chunk (1024/8)

__global__ void prep_kernel(const float* __restrict__ means,
                            const float* __restrict__ scales,
                            const float* __restrict__ rots,
                            const float* __restrict__ ops,
                            const float* __restrict__ fts,
                            float4* __restrict__ gdata) {
    __shared__ float red[256];
    int tid = threadIdx.x;

    // block-redundant max over scales[:,2]  (removes a separate dispatch)
    float m = -1e30f;
    for (int i = tid; i < NG; i += 256) m = fmaxf(m, scales[i*3+2]);
    red[tid] = m;
    __syncthreads();
    for (int s = 128; s > 0; s >>= 1) {
        if (tid < s) red[tid] = fmaxf(red[tid], red[tid+s]);
        __syncthreads();
    }
    float maxd = 3.0f * red[0];

    int g = blockIdx.x * 256 + tid;
    if (g >= NG) return;

    float qw = rots[g*4+0], qx = rots[g*4+1], qy = rots[g*4+2], qz = rots[g*4+3];
    float inorm = rsqrtf(qw*qw + qx*qx + qy*qy + qz*qz);
    qw *= inorm; qx *= inorm; qy *= inorm; qz *= inorm;

    float s0 = scales[g*3+0], s1 = scales[g*3+1], s2 = scales[g*3+2];

    float r00 = 1.f - 2.f*(qy*qy + qz*qz), r01 = 2.f*(qx*qy - qw*qz), r02 = 2.f*(qx*qz + qw*qy);
    float r10 = 2.f*(qx*qy + qw*qz), r11 = 1.f - 2.f*(qx*qx + qz*qz), r12 = 2.f*(qy*qz - qw*qx);
    float r20 = 2.f*(qx*qz - qw*qy), r21 = 2.f*(qy*qz + qw*qx), r22 = 1.f - 2.f*(qx*qx + qy*qy);

    float a00 = r00*s0, a01 = r01*s1, a02 = r02*s2;
    float a10 = r10*s0, a11 = r11*s1, a12 = r12*s2;
    float a20 = r20*s0, a21 = r21*s1, a22 = r22*s2;

    float c00 = a00*a00 + a01*a01 + a02*a02;
    float c01 = a00*a10 + a01*a11 + a02*a12;
    float c02 = a00*a20 + a01*a21 + a02*a22;
    float c11 = a10*a10 + a11*a11 + a12*a12;
    float c12 = a10*a20 + a11*a21 + a12*a22;
    float c22 = a20*a20 + a21*a21 + a22*a22;

    float izz = 1.0f / (c22 + EPSV);
    float kx = c02 * izz, ky = c12 * izz;
    float sa = c00 - c02*c02*izz + EPSV;
    float sb = c01 - c02*c12*izz;
    float sd = c11 - c12*c12*izz + EPSV;
    float det = sa*sd - sb*sb;
    float idet = 1.0f / det;

    const float C0 = -0.72134752044448170f;   // -0.5 * log2(e)
    float qa = C0 * sd * idet;
    float qb = C0 * (-2.0f * sb * idet);
    float qd = C0 * sa * idet;

    float mx = means[g*3+0], my = means[g*3+1], mz = means[g*3+2];
    float op = ops[g], ft = fts[g];

    #pragma unroll
    for (int s = 0; s < NSL; ++s) {
        float z = -0.15f + 0.1f * (float)s;
        float zoff = z - mz;
        float m2x = mx + kx * zoff;
        float m2y = my + ky * zoff;
        bool live = (fabsf(mz - z) < maxd) && (op > 1e-12f);
        float lop  = live ? __log2f(op) : -__builtin_inff();
        float ftop = live ? ft / op     : 0.f;
        gdata[(s*NG + g)*2 + 0] = make_float4(m2x, m2y, qa, qb);
        gdata[(s*NG + g)*2 + 1] = make_float4(qd, lop, ftop, 0.f);
    }
}

__global__ __launch_bounds__(512, 8)
void render_kernel(const float4* __restrict__ gdata, float* __restrict__ out) {
    __shared__ float parts[SPLIT][PXW][9];   // +1 pad: 9 floats -> conflict-free

    int tid   = threadIdx.x;
    int px    = tid & 63;
    int split = __builtin_amdgcn_readfirstlane(tid >> 6);  // wave-uniform by construction
    int slice = blockIdx.x >> 8;
    int tile  = blockIdx.x & 255;
    int pxg   = tile * PXW + px;
    int row   = pxg >> 7, col = pxg & 127;
    float x = (float)col * (2.0f/127.0f) - 1.0f;
    float y = (float)row * (2.0f/127.0f) - 1.0f;

    const float4* gs = gdata + slice * (NG*2);

    #pragma unroll
    for (int c = 0; c < 4; ++c) {
        const float4* p = gs + (size_t)(c*1024 + split*GPW) * 2;  // uniform address
        float a1 = 0.f, a2 = 0.f;
        #pragma unroll 8
        for (int g = 0; g < GPW; ++g) {
            float4 A = p[2*g+0];           // m2x, m2y, qa, qb   (s_load -> SGPR)
            float4 B = p[2*g+1];           // qd, lop, ftop, pad
            float dx = x - A.x;
            float dy = y - A.y;
            float t  = fmaf(A.z, dx, A.w * dy);   // qa*dx + qb*dy
            float e  = fmaf(B.x * dy, dy, B.y);   // qd*dy^2 + log2(op*mask)
            float mm = fmaf(dx, t, e);
            float gv = __builtin_amdgcn_exp2f(mm);   // = g*op
            a1 += gv;
            a2 = fmaf(gv * gv, B.z, a2);             // (g*op)^2 * ft/op
        }
        parts[split][px][c]     = a1;
        parts[split][px][c + 4] = a2;
    }
    __syncthreads();

    if (tid < 64) {
        float img = 0.f, acc = 0.f;
        #pragma unroll
        for (int c = 0; c < 4; ++c) {
            float S1 = 0.f, S2 = 0.f;
            #pragma unroll
            for (int s = 0; s < SPLIT; ++s) {
                S1 += parts[s][px][c];
                S2 += parts[s][px][c + 4];
            }
            float om = 1.0f - acc;
            img = fmaf(om, S2, img);
            acc = fmaf(om, S1, acc);
        }
        out[slice * PP + pxg] = img;
    }
}

extern "C" void kernel_launch(void* const* d_in, const int* in_sizes, int n_in,
                              void* d_out, int out_size, void* d_ws, size_t ws_size,
                              hipStream_t stream) {
    const float* means  = (const float*)d_in[0];
    const float* scales = (const float*)d_in[1];
    const float* rots   = (const float*)d_in[2];
    const float* ops    = (const float*)d_in[3];
    const float* fts    = (const float*)d_in[4];
    float* out = (float*)d_out;

    float4* gdata = (float4*)d_ws;   // 4*4096*2 float4 = 512 KB

    prep_kernel<<<NG/256, 256, 0, stream>>>(means, scales, rots, ops, fts, gdata);
    render_kernel<<<NSL*(PP/PXW), 512, 0, stream>>>(gdata, out);
}